// Round 1
// baseline (471.066 us; speedup 1.0000x reference)
//
#include <hip/hip_runtime.h>

// WindowAttention: B=256 windows, N=256 tokens, C=384, 12 heads, d=32.
// Pipeline: K0 cast weights->bf16 | K1 transpose-cast x (B,C,N)f32 -> xt (B*N,C)bf16
//           K2 per-(b,h): qkv MFMA GEMM + l2norm + MFMA attention -> attn (B*N,C)bf16
//           K3 proj MFMA GEMM + output transpose -> (B,C,N) f32
// MFMA 16x16x32 bf16 layouts (verified m89/m91/m120):
//   A: A[m][k] m=lane&15, k=(lane>>4)*8+j ; B: B[k][n] n=lane&15, k=(lane>>4)*8+j
//   D: col=lane&15, row=(lane>>4)*4+r
// Softmax: logits = SCALE*(qhat.khat) in [-0.178,0.178] -> no max-subtract needed,
// clip(1e-6,1) provably no-op (probs in [2.7e-3, 5.5e-3]). SCALE folded into qhat.
// R1 changes vs 489us baseline:
//  (a) XCD-pinned block swizzle in K2/K3: all sibling blocks of a batch land on one
//      XCD -> token slab fetched LLC->L2 once instead of 12x (K2) / 4x (K3).
//  (b) Phase C software pipeline: next chunk's S-MFMAs issued between P-stores and
//      the pa read-back, covering the ds_write->ds_read drain latency.
//  (c) SCALE folded into qn store (kills 8 v_mul per key-chunk in the exp path).

#define DIM 384
#define NT 256
#define NH 12
#define HD 32
#define SCALE 0.17677669529663687f

typedef __bf16 bf16;
typedef __bf16 bf16x8 __attribute__((ext_vector_type(8)));
typedef float f32x4 __attribute__((ext_vector_type(4)));

#define MFMA16(a, b, c) __builtin_amdgcn_mfma_f32_16x16x32_bf16(a, b, c, 0, 0, 0)

// ---------------- K0: cast weights to bf16 ----------------
__global__ void k_cast_w(const float* __restrict__ qkv_w, const float* __restrict__ proj_w,
                         bf16* __restrict__ wq, bf16* __restrict__ wp) {
    int i = blockIdx.x * 256 + threadIdx.x;
    if (i < 3 * DIM * DIM) wq[i] = (bf16)qkv_w[i];
    if (i < DIM * DIM)     wp[i] = (bf16)proj_w[i];
}

// ---------------- K1: x (B,C,N) f32 -> xt (B*N, C) bf16 ----------------
__global__ void k_transpose_cast(const float* __restrict__ x, bf16* __restrict__ xt) {
    __shared__ float tile[32][33];
    int b = blockIdx.z;
    int c0 = blockIdx.y * 32;
    int n0 = blockIdx.x * 32;
    int tx = threadIdx.x, ty = threadIdx.y;
    const float* xp = x + (size_t)b * DIM * NT;
#pragma unroll
    for (int i = 0; i < 4; ++i) {
        int c = c0 + ty + i * 8;
        tile[ty + i * 8][tx] = xp[(size_t)c * NT + n0 + tx];
    }
    __syncthreads();
    bf16* op = xt + (size_t)b * NT * DIM;
#pragma unroll
    for (int i = 0; i < 4; ++i) {
        int n = n0 + ty + i * 8;
        op[(size_t)n * DIM + c0 + tx] = (bf16)tile[tx][ty + i * 8];
    }
}

// ---------------- K2: fused qkv GEMM + l2norm + attention, one block per (b,h) ----------------
__launch_bounds__(256, 2)
__global__ void k_qkv_attn(const bf16* __restrict__ xt, const bf16* __restrict__ wq,
                           const float* __restrict__ qkv_b, bf16* __restrict__ attn_out) {
    // LDS: 20480*2 + 16896 + 5120 + 384 = 63360 B  -> 2 blocks/CU
    __shared__ bf16 qn[NT][40];       // normalized q*SCALE, bf16, row pad 40 (80B, 16B-mult)
    __shared__ bf16 kn[NT][40];       // normalized k
    __shared__ bf16 vT[HD][264];      // v transposed [d][token], pad 264 (528B)
    __shared__ bf16 pbuf[4][16][40];  // per-wave P chunk: 16 queries x 32 keys
    __shared__ float bias_s[96];

    // XCD-pinned decode: block n is heuristically scheduled on XCD n%8. Give each
    // XCD a contiguous 32-batch slice; all 12 head-blocks of a batch share one L2,
    // so the 196KB xt slab is pulled from LLC once instead of 12x.
    const int n_ = blockIdx.x;            // grid = 3072 (bijective remap of (h,b))
    const int xcd = n_ & 7;
    const int ww = n_ >> 3;               // 0..383
    const int b = xcd * 32 + ww / 12;
    const int h = ww % 12;

    const int tid = threadIdx.x;
    const int lane = tid & 63, w = tid >> 6;
    const int l15 = lane & 15, quad = lane >> 4;

    if (tid < 96) {
        int which = tid >> 5;
        bias_s[tid] = qkv_b[which * DIM + h * HD + (tid & 31)];
    }
    __syncthreads();

    // ---- Phase A: qkv GEMM. Wave w owns tokens [w*64, w*64+64), all 96 outputs j.
    // D[j][tok]: A = Wqkv rows (96 x 384), B = xt tokens (384 x 64). Direct global frag loads.
    f32x4 acc[6][4];
#pragma unroll
    for (int jt = 0; jt < 6; ++jt)
#pragma unroll
        for (int tt = 0; tt < 4; ++tt) acc[jt][tt] = (f32x4){0.f, 0.f, 0.f, 0.f};

    const bf16* xrow[4];
#pragma unroll
    for (int tt = 0; tt < 4; ++tt) {
        int tok = w * 64 + tt * 16 + l15;
        xrow[tt] = xt + (size_t)(b * NT + tok) * DIM + quad * 8;
    }
    const bf16* wrow[6];
#pragma unroll
    for (int jt = 0; jt < 6; ++jt) {
        int jj = jt * 16 + l15;
        int which = jj >> 5;
        wrow[jt] = wq + (size_t)(which * DIM + h * HD + (jj & 31)) * DIM + quad * 8;
    }

#pragma unroll 2
    for (int kc = 0; kc < 12; ++kc) {
        int k0 = kc * 32;
        bf16x8 bfr[4], afr[6];
#pragma unroll
        for (int tt = 0; tt < 4; ++tt) bfr[tt] = *(const bf16x8*)(xrow[tt] + k0);
#pragma unroll
        for (int jt = 0; jt < 6; ++jt) afr[jt] = *(const bf16x8*)(wrow[jt] + k0);
#pragma unroll
        for (int jt = 0; jt < 6; ++jt)
#pragma unroll
            for (int tt = 0; tt < 4; ++tt)
                acc[jt][tt] = MFMA16(afr[jt], bfr[tt], acc[jt][tt]);
    }

    // ---- epilogue: +bias, l2-normalize q,k (cross-quad shfl reduce), write bf16 LDS ----
#pragma unroll
    for (int tt = 0; tt < 4; ++tt) {
        int tok = w * 64 + tt * 16 + l15;  // = D col for this frag
        float v[6][4];
        float sq = 0.f, sk = 0.f;
#pragma unroll
        for (int jt = 0; jt < 6; ++jt)
#pragma unroll
            for (int r = 0; r < 4; ++r) {
                int j = jt * 16 + quad * 4 + r;  // D row
                float t = acc[jt][tt][r] + bias_s[j];
                v[jt][r] = t;
                if (jt < 2) sq += t * t;
                else if (jt < 4) sk += t * t;
            }
        // rows of a token are spread across the 4 quads -> reduce over lane^16, lane^32
        sq += __shfl_xor(sq, 16); sq += __shfl_xor(sq, 32);
        sk += __shfl_xor(sk, 16); sk += __shfl_xor(sk, 32);
        float iq = SCALE / fmaxf(sqrtf(sq), 1e-12f);   // fold attention scale into qhat
        float ik = 1.f / fmaxf(sqrtf(sk), 1e-12f);
#pragma unroll
        for (int jt = 0; jt < 6; ++jt)
#pragma unroll
            for (int r = 0; r < 4; ++r) {
                int j = jt * 16 + quad * 4 + r;
                if (j < 32)      qn[tok][j]      = (bf16)(v[jt][r] * iq);
                else if (j < 64) kn[tok][j - 32] = (bf16)(v[jt][r] * ik);
                else             vT[j - 64][tok] = (bf16)v[jt][r];
            }
    }
    __syncthreads();

    // ---- Phase C: attention. Wave w owns queries [w*64, w*64+64).
    // Software pipeline: while chunk kt's P-stores drain in LDS, issue chunk kt+1's
    // S-MFMAs; pa read-back then no longer stalls on lgkmcnt.
    const f32x4 zf = {0.f, 0.f, 0.f, 0.f};
#pragma unroll 1
    for (int qt = 0; qt < 4; ++qt) {
        int nq0 = w * 64 + qt * 16;
        bf16x8 qa = *(const bf16x8*)&qn[nq0 + l15][quad * 8];  // A-frag: m=query
        f32x4 o0 = zf, o1 = zf;
        float dsm[4] = {0.f, 0.f, 0.f, 0.f};

        // prologue: S for kt=0 (keys 0..31). logits already scaled (SCALE in qhat).
        f32x4 s0 = MFMA16(qa, *(const bf16x8*)&kn[l15][quad * 8], zf);
        f32x4 s1 = MFMA16(qa, *(const bf16x8*)&kn[16 + l15][quad * 8], zf);

#pragma unroll 2
        for (int kt = 0; kt < 8; ++kt) {  // 32 keys per chunk
            // exp + store current chunk's P (C-layout row=query, col=key)
            float p0[4], p1[4];
#pragma unroll
            for (int r = 0; r < 4; ++r) {
                p0[r] = __expf(s0[r]);
                p1[r] = __expf(s1[r]);
                dsm[r] += p0[r] + p1[r];
                pbuf[w][quad * 4 + r][l15]      = (bf16)p0[r];
                pbuf[w][quad * 4 + r][16 + l15] = (bf16)p1[r];
            }
            // prefetch next chunk's S while the stores drain (covers lgkm latency)
            if (kt < 7) {
                int nk0 = kt * 32 + 32;
                s0 = MFMA16(qa, *(const bf16x8*)&kn[nk0 + l15][quad * 8], zf);
                s1 = MFMA16(qa, *(const bf16x8*)&kn[nk0 + 16 + l15][quad * 8], zf);
            }
            // P (C-layout) -> A-layout via LDS round-trip; PV MFMA
            bf16x8 vb0 = *(const bf16x8*)&vT[l15][kt * 32 + quad * 8];
            bf16x8 vb1 = *(const bf16x8*)&vT[16 + l15][kt * 32 + quad * 8];
            bf16x8 pa  = *(const bf16x8*)&pbuf[w][l15][quad * 8];
            o0 = MFMA16(pa, vb0, o0);
            o1 = MFMA16(pa, vb1, o1);
        }
        // full denom per query: reduce over the 16 lanes of each quad
#pragma unroll
        for (int r = 0; r < 4; ++r) {
            dsm[r] += __shfl_xor(dsm[r], 1);
            dsm[r] += __shfl_xor(dsm[r], 2);
            dsm[r] += __shfl_xor(dsm[r], 4);
            dsm[r] += __shfl_xor(dsm[r], 8);
        }
        bf16* op = attn_out + (size_t)(b * NT + nq0) * DIM + h * HD;
#pragma unroll
        for (int r = 0; r < 4; ++r) {
            float inv = 1.f / dsm[r];
            int nq = quad * 4 + r;  // O row = query
            op[(size_t)nq * DIM + l15]      = (bf16)(o0[r] * inv);
            op[(size_t)nq * DIM + 16 + l15] = (bf16)(o1[r] * inv);
        }
    }
}

// ---------------- K3: proj GEMM + output transpose ----------------
__launch_bounds__(256, 2)
__global__ void k_proj(const bf16* __restrict__ xa, const bf16* __restrict__ wp,
                       const float* __restrict__ proj_b, float* __restrict__ out) {
    __shared__ float bias_s[96];
    // XCD-pinned decode (grid = 1024): 4 cb-blocks of a batch share one L2.
    const int n_ = blockIdx.x;
    const int xcd = n_ & 7;
    const int ww = n_ >> 3;               // 0..127
    const int b  = xcd * 32 + (ww >> 2);
    const int cb = ww & 3;                // 96-wide slice of 384 out channels

    const int tid = threadIdx.x;
    const int lane = tid & 63, w = tid >> 6;
    const int l15 = lane & 15, quad = lane >> 4;
    if (tid < 96) bias_s[tid] = proj_b[cb * 96 + tid];
    __syncthreads();

    f32x4 acc[6][4];
#pragma unroll
    for (int jt = 0; jt < 6; ++jt)
#pragma unroll
        for (int tt = 0; tt < 4; ++tt) acc[jt][tt] = (f32x4){0.f, 0.f, 0.f, 0.f};

    const bf16* arow[6];
#pragma unroll
    for (int jt = 0; jt < 6; ++jt)
        arow[jt] = wp + (size_t)(cb * 96 + jt * 16 + l15) * DIM + quad * 8;
    const bf16* brow[4];
#pragma unroll
    for (int tt = 0; tt < 4; ++tt)
        brow[tt] = xa + (size_t)(b * NT + w * 64 + tt * 16 + l15) * DIM + quad * 8;

#pragma unroll 2
    for (int kc = 0; kc < 12; ++kc) {
        int k0 = kc * 32;
        bf16x8 bfr[4], afr[6];
#pragma unroll
        for (int tt = 0; tt < 4; ++tt) bfr[tt] = *(const bf16x8*)(brow[tt] + k0);
#pragma unroll
        for (int jt = 0; jt < 6; ++jt) afr[jt] = *(const bf16x8*)(arow[jt] + k0);
#pragma unroll
        for (int jt = 0; jt < 6; ++jt)
#pragma unroll
            for (int tt = 0; tt < 4; ++tt)
                acc[jt][tt] = MFMA16(afr[jt], bfr[tt], acc[jt][tt]);
    }

    float* op = out + (size_t)b * DIM * NT;  // out[b][c][n]
#pragma unroll
    for (int jt = 0; jt < 6; ++jt)
#pragma unroll
        for (int tt = 0; tt < 4; ++tt)
#pragma unroll
            for (int r = 0; r < 4; ++r) {
                int cl = jt * 16 + quad * 4 + r;          // D row = out channel (local)
                int n  = w * 64 + tt * 16 + l15;          // D col = token
                op[(size_t)(cb * 96 + cl) * NT + n] = acc[jt][tt][r] + bias_s[cl];
            }
}

extern "C" void kernel_launch(void* const* d_in, const int* in_sizes, int n_in,
                              void* d_out, int out_size, void* d_ws, size_t ws_size,
                              hipStream_t stream) {
    const float* x      = (const float*)d_in[0];
    const float* qkv_w  = (const float*)d_in[1];
    const float* qkv_b  = (const float*)d_in[2];
    const float* proj_w = (const float*)d_in[3];
    const float* proj_b = (const float*)d_in[4];
    float* out = (float*)d_out;

    char* ws = (char*)d_ws;
    bf16* xt = (bf16*)ws;                    // 256*256*384*2 = 50,331,648 B
    bf16* xa = (bf16*)(ws + 50331648);       // 50,331,648 B
    bf16* wq = (bf16*)(ws + 100663296);      // 884,736 B
    bf16* wp = (bf16*)(ws + 101548032);      // 294,912 B  (total 101,842,944 B)

    k_cast_w<<<dim3(1728), dim3(256), 0, stream>>>(qkv_w, proj_w, wq, wp);
    k_transpose_cast<<<dim3(8, 12, 256), dim3(32, 8), 0, stream>>>(x, xt);
    k_qkv_attn<<<dim3(NH * 256), dim3(256), 0, stream>>>(xt, wq, qkv_b, xa);
    k_proj<<<dim3(4 * 256), dim3(256), 0, stream>>>(xa, wp, proj_b, out);
}

// Round 2
// 461.934 us; speedup vs baseline: 1.0198x; 1.0198x over previous
//
#include <hip/hip_runtime.h>

// WindowAttention: B=256 windows, N=256 tokens, C=384, 12 heads, d=32.
// Pipeline: K0 cast weights->bf16 | K1 transpose-cast x (B,C,N)f32 -> xt (B*N,C)bf16
//           K2 per-(b,h): qkv MFMA GEMM + l2norm + MFMA attention -> attn (B*N,C)bf16
//           K3 proj MFMA GEMM + output transpose -> (B,C,N) f32
// MFMA 16x16x32 bf16 layouts (verified m89/m91/m120):
//   A: A[m][k] m=lane&15, k=(lane>>4)*8+j ; B: B[k][n] n=lane&15, k=(lane>>4)*8+j
//   D: col=lane&15, row=(lane>>4)*4+r
// Softmax: logits = SCALE*(qhat.khat) in [-0.178,0.178] -> no max-subtract needed,
// clip(1e-6,1) provably no-op (probs in [2.7e-3, 5.5e-3]). SCALE and 1/ln2 folded
// into qhat so p = v_exp_f32(s) directly.
// R2 changes vs 471us/K2=237us:
//  (a) 3 blocks/CU: LDS 63360->54144 (qn unpadded [256][32]; per-wave pbuf aliased
//      into the wave's own qn slice after q-frags are hoisted to VGPRs).
//  (b) QK^T operand swap (S^T = MFMA(K,Q)): lane's 4 D-regs = 4 consecutive keys of
//      ONE query -> P-store is 2x ds_write_b64 (was 8x b16 w/ 4-way conflicts);
//      denom = per-lane scalar (2 shfl + 4 bpermute, was 16 shfl).
//  (c) kt-outer/qt-inner: K/V frags loaded once per 32-key chunk (LDS ops 28->16).

#define DIM 384
#define NT 256
#define NH 12
#define HD 32
#define SCALE 0.17677669529663687f
#define QSCALE (0.17677669529663687f * 1.4426950408889634f)  // SCALE/ln2

typedef __bf16 bf16;
typedef __bf16 bf16x4 __attribute__((ext_vector_type(4)));
typedef __bf16 bf16x8 __attribute__((ext_vector_type(8)));
typedef float f32x4 __attribute__((ext_vector_type(4)));

#define MFMA16(a, b, c) __builtin_amdgcn_mfma_f32_16x16x32_bf16(a, b, c, 0, 0, 0)

// ---------------- K0: cast weights to bf16 ----------------
__global__ void k_cast_w(const float* __restrict__ qkv_w, const float* __restrict__ proj_w,
                         bf16* __restrict__ wq, bf16* __restrict__ wp) {
    int i = blockIdx.x * 256 + threadIdx.x;
    if (i < 3 * DIM * DIM) wq[i] = (bf16)qkv_w[i];
    if (i < DIM * DIM)     wp[i] = (bf16)proj_w[i];
}

// ---------------- K1: x (B,C,N) f32 -> xt (B*N, C) bf16 ----------------
__global__ void k_transpose_cast(const float* __restrict__ x, bf16* __restrict__ xt) {
    __shared__ float tile[32][33];
    int b = blockIdx.z;
    int c0 = blockIdx.y * 32;
    int n0 = blockIdx.x * 32;
    int tx = threadIdx.x, ty = threadIdx.y;
    const float* xp = x + (size_t)b * DIM * NT;
#pragma unroll
    for (int i = 0; i < 4; ++i) {
        int c = c0 + ty + i * 8;
        tile[ty + i * 8][tx] = xp[(size_t)c * NT + n0 + tx];
    }
    __syncthreads();
    bf16* op = xt + (size_t)b * NT * DIM;
#pragma unroll
    for (int i = 0; i < 4; ++i) {
        int n = n0 + ty + i * 8;
        op[(size_t)n * DIM + c0 + tx] = (bf16)tile[tx][ty + i * 8];
    }
}

// ---------------- K2: fused qkv GEMM + l2norm + attention, one block per (b,h) ----------------
__launch_bounds__(256, 3)
__global__ void k_qkv_attn(const bf16* __restrict__ xt, const bf16* __restrict__ wq,
                           const float* __restrict__ qkv_b, bf16* __restrict__ attn_out) {
    // LDS: kn 20480 + vT 16896 + qn 16384 + bias 384 = 54144 B -> 3 blocks/CU
    __shared__ bf16 kn[NT][40];       // normalized k, row pad 40 (80B)
    __shared__ bf16 vT[HD][264];      // v transposed [d][token], pad 264 (528B)
    __shared__ bf16 qn[NT][32];       // normalized q*QSCALE; wave's slice reused as pbuf
    __shared__ float bias_s[96];

    // XCD-pinned decode: all 12 head-blocks of a batch share one XCD/L2.
    const int n_ = blockIdx.x;            // grid = 3072 (bijective remap of (h,b))
    const int xcd = n_ & 7;
    const int ww = n_ >> 3;               // 0..383
    const int b = xcd * 32 + ww / 12;
    const int h = ww % 12;

    const int tid = threadIdx.x;
    const int lane = tid & 63, w = tid >> 6;
    const int l15 = lane & 15, quad = lane >> 4;

    if (tid < 96) {
        int which = tid >> 5;
        bias_s[tid] = qkv_b[which * DIM + h * HD + (tid & 31)];
    }
    __syncthreads();

    // ---- Phase A: qkv GEMM. Wave w owns tokens [w*64, w*64+64), all 96 outputs j.
    f32x4 acc[6][4];
#pragma unroll
    for (int jt = 0; jt < 6; ++jt)
#pragma unroll
        for (int tt = 0; tt < 4; ++tt) acc[jt][tt] = (f32x4){0.f, 0.f, 0.f, 0.f};

    const bf16* xrow[4];
#pragma unroll
    for (int tt = 0; tt < 4; ++tt) {
        int tok = w * 64 + tt * 16 + l15;
        xrow[tt] = xt + (size_t)(b * NT + tok) * DIM + quad * 8;
    }
    const bf16* wrow[6];
#pragma unroll
    for (int jt = 0; jt < 6; ++jt) {
        int jj = jt * 16 + l15;
        int which = jj >> 5;
        wrow[jt] = wq + (size_t)(which * DIM + h * HD + (jj & 31)) * DIM + quad * 8;
    }

#pragma unroll 2
    for (int kc = 0; kc < 12; ++kc) {
        int k0 = kc * 32;
        bf16x8 bfr[4], afr[6];
#pragma unroll
        for (int tt = 0; tt < 4; ++tt) bfr[tt] = *(const bf16x8*)(xrow[tt] + k0);
#pragma unroll
        for (int jt = 0; jt < 6; ++jt) afr[jt] = *(const bf16x8*)(wrow[jt] + k0);
#pragma unroll
        for (int jt = 0; jt < 6; ++jt)
#pragma unroll
            for (int tt = 0; tt < 4; ++tt)
                acc[jt][tt] = MFMA16(afr[jt], bfr[tt], acc[jt][tt]);
    }

    // ---- epilogue: +bias, l2-normalize q,k (cross-quad shfl reduce), write bf16 LDS ----
#pragma unroll
    for (int tt = 0; tt < 4; ++tt) {
        int tok = w * 64 + tt * 16 + l15;  // = D col for this frag
        float v[6][4];
        float sq = 0.f, sk = 0.f;
#pragma unroll
        for (int jt = 0; jt < 6; ++jt)
#pragma unroll
            for (int r = 0; r < 4; ++r) {
                int j = jt * 16 + quad * 4 + r;  // D row
                float t = acc[jt][tt][r] + bias_s[j];
                v[jt][r] = t;
                if (jt < 2) sq += t * t;
                else if (jt < 4) sk += t * t;
            }
        sq += __shfl_xor(sq, 16); sq += __shfl_xor(sq, 32);
        sk += __shfl_xor(sk, 16); sk += __shfl_xor(sk, 32);
        float iq = QSCALE / fmaxf(sqrtf(sq), 1e-12f);  // scale + 1/ln2 folded into qhat
        float ik = 1.f / fmaxf(sqrtf(sk), 1e-12f);
#pragma unroll
        for (int jt = 0; jt < 6; ++jt)
#pragma unroll
            for (int r = 0; r < 4; ++r) {
                int j = jt * 16 + quad * 4 + r;
                if (j < 32)      qn[tok][j]      = (bf16)(v[jt][r] * iq);
                else if (j < 64) kn[tok][j - 32] = (bf16)(v[jt][r] * ik);
                else             vT[j - 64][tok] = (bf16)v[jt][r];
            }
    }
    __syncthreads();

    // ---- Phase C: attention, kt-outer / qt-inner. Wave w owns queries [w*64, w*64+64).
    // Hoist all 4 q A-frags to VGPRs, then reuse the wave's own qn slice as pbuf.
    bf16x8 qa[4];
#pragma unroll
    for (int qt = 0; qt < 4; ++qt)
        qa[qt] = *(const bf16x8*)&qn[w * 64 + qt * 16 + l15][quad * 8];

    bf16* pw = &qn[w * 64][0];  // wave-private 4096B region; 2 sections of [16][40]

    const f32x4 zf = {0.f, 0.f, 0.f, 0.f};
    f32x4 o[4][2];
#pragma unroll
    for (int qt = 0; qt < 4; ++qt) { o[qt][0] = zf; o[qt][1] = zf; }
    float dsm[4] = {0.f, 0.f, 0.f, 0.f};

#pragma unroll 1
    for (int kt = 0; kt < 8; ++kt) {  // 32 keys per chunk
        int nk0 = kt * 32;
        // K A-frags + V B-frags for this chunk (qt-invariant)
        bf16x8 kb0 = *(const bf16x8*)&kn[nk0 + l15][quad * 8];
        bf16x8 kb1 = *(const bf16x8*)&kn[nk0 + 16 + l15][quad * 8];
        bf16x8 vb0 = *(const bf16x8*)&vT[l15][nk0 + quad * 8];
        bf16x8 vb1 = *(const bf16x8*)&vT[16 + l15][nk0 + quad * 8];

        // S^T = MFMA(K, Q): lane holds keys nk0+(st*16)+quad*4+r at query base+l15
        f32x4 s0 = MFMA16(kb0, qa[0], zf);
        f32x4 s1 = MFMA16(kb1, qa[0], zf);
#pragma unroll
        for (int qt = 0; qt < 4; ++qt) {
            bf16x4 P0, P1;
            float d0 = 0.f;
#pragma unroll
            for (int r = 0; r < 4; ++r) {
                float p0 = __builtin_amdgcn_exp2f(s0[r]);  // scale/ln2 pre-folded
                float p1 = __builtin_amdgcn_exp2f(s1[r]);
                d0 += p0 + p1;
                P0[r] = (bf16)p0;
                P1[r] = (bf16)p1;
            }
            dsm[qt] += d0;
            // P chunk in [query][key] layout: lane's 4 regs = 4 consecutive keys
            bf16* sect = pw + (qt & 1) * 640;
            *(bf16x4*)&sect[l15 * 40 + quad * 4]      = P0;
            *(bf16x4*)&sect[l15 * 40 + 16 + quad * 4] = P1;
            // prefetch next qt's S while stores drain
            if (qt < 3) {
                s0 = MFMA16(kb0, qa[qt + 1], zf);
                s1 = MFMA16(kb1, qa[qt + 1], zf);
            }
            // PV: pa = P[query l15][key quad*8..+7] (b128)
            bf16x8 pa = *(const bf16x8*)&sect[l15 * 40 + quad * 8];
            o[qt][0] = MFMA16(pa, vb0, o[qt][0]);
            o[qt][1] = MFMA16(pa, vb1, o[qt][1]);
        }
    }

    // denom: reduce per-lane partials over the 4 quads -> full denom for query base+l15
#pragma unroll
    for (int qt = 0; qt < 4; ++qt) {
        dsm[qt] += __shfl_xor(dsm[qt], 16);
        dsm[qt] += __shfl_xor(dsm[qt], 32);
    }
    bf16* opbase = attn_out + (size_t)(b * NT + w * 64) * DIM + h * HD;
#pragma unroll
    for (int qt = 0; qt < 4; ++qt)
#pragma unroll
        for (int r = 0; r < 4; ++r) {
            // O row = query quad*4+r; its denom lives at lanes with l15 == quad*4+r
            float inv = 1.f / __shfl(dsm[qt], quad * 4 + r);
            int nq = qt * 16 + quad * 4 + r;
            opbase[(size_t)nq * DIM + l15]      = (bf16)(o[qt][0][r] * inv);
            opbase[(size_t)nq * DIM + 16 + l15] = (bf16)(o[qt][1][r] * inv);
        }
}

// ---------------- K3: proj GEMM + output transpose ----------------
__launch_bounds__(256, 2)
__global__ void k_proj(const bf16* __restrict__ xa, const bf16* __restrict__ wp,
                       const float* __restrict__ proj_b, float* __restrict__ out) {
    __shared__ float bias_s[96];
    // XCD-pinned decode (grid = 1024): 4 cb-blocks of a batch share one L2.
    const int n_ = blockIdx.x;
    const int xcd = n_ & 7;
    const int ww = n_ >> 3;               // 0..127
    const int b  = xcd * 32 + (ww >> 2);
    const int cb = ww & 3;                // 96-wide slice of 384 out channels

    const int tid = threadIdx.x;
    const int lane = tid & 63, w = tid >> 6;
    const int l15 = lane & 15, quad = lane >> 4;
    if (tid < 96) bias_s[tid] = proj_b[cb * 96 + tid];
    __syncthreads();

    f32x4 acc[6][4];
#pragma unroll
    for (int jt = 0; jt < 6; ++jt)
#pragma unroll
        for (int tt = 0; tt < 4; ++tt) acc[jt][tt] = (f32x4){0.f, 0.f, 0.f, 0.f};

    const bf16* arow[6];
#pragma unroll
    for (int jt = 0; jt < 6; ++jt)
        arow[jt] = wp + (size_t)(cb * 96 + jt * 16 + l15) * DIM + quad * 8;
    const bf16* brow[4];
#pragma unroll
    for (int tt = 0; tt < 4; ++tt)
        brow[tt] = xa + (size_t)(b * NT + w * 64 + tt * 16 + l15) * DIM + quad * 8;

#pragma unroll 2
    for (int kc = 0; kc < 12; ++kc) {
        int k0 = kc * 32;
        bf16x8 bfr[4], afr[6];
#pragma unroll
        for (int tt = 0; tt < 4; ++tt) bfr[tt] = *(const bf16x8*)(brow[tt] + k0);
#pragma unroll
        for (int jt = 0; jt < 6; ++jt) afr[jt] = *(const bf16x8*)(arow[jt] + k0);
#pragma unroll
        for (int jt = 0; jt < 6; ++jt)
#pragma unroll
            for (int tt = 0; tt < 4; ++tt)
                acc[jt][tt] = MFMA16(afr[jt], bfr[tt], acc[jt][tt]);
    }

    float* op = out + (size_t)b * DIM * NT;  // out[b][c][n]
#pragma unroll
    for (int jt = 0; jt < 6; ++jt)
#pragma unroll
        for (int tt = 0; tt < 4; ++tt)
#pragma unroll
            for (int r = 0; r < 4; ++r) {
                int cl = jt * 16 + quad * 4 + r;          // D row = out channel (local)
                int n  = w * 64 + tt * 16 + l15;          // D col = token
                op[(size_t)(cb * 96 + cl) * NT + n] = acc[jt][tt][r] + bias_s[cl];
            }
}

extern "C" void kernel_launch(void* const* d_in, const int* in_sizes, int n_in,
                              void* d_out, int out_size, void* d_ws, size_t ws_size,
                              hipStream_t stream) {
    const float* x      = (const float*)d_in[0];
    const float* qkv_w  = (const float*)d_in[1];
    const float* qkv_b  = (const float*)d_in[2];
    const float* proj_w = (const float*)d_in[3];
    const float* proj_b = (const float*)d_in[4];
    float* out = (float*)d_out;

    char* ws = (char*)d_ws;
    bf16* xt = (bf16*)ws;                    // 256*256*384*2 = 50,331,648 B
    bf16* xa = (bf16*)(ws + 50331648);       // 50,331,648 B
    bf16* wq = (bf16*)(ws + 100663296);      // 884,736 B
    bf16* wp = (bf16*)(ws + 101548032);      // 294,912 B  (total 101,842,944 B)

    k_cast_w<<<dim3(1728), dim3(256), 0, stream>>>(qkv_w, proj_w, wq, wp);
    k_transpose_cast<<<dim3(8, 12, 256), dim3(32, 8), 0, stream>>>(x, xt);
    k_qkv_attn<<<dim3(NH * 256), dim3(256), 0, stream>>>(xt, wq, qkv_b, xa);
    k_proj<<<dim3(4 * 256), dim3(256), 0, stream>>>(xa, wp, proj_b, out);
}